// Round 11
// baseline (161.845 us; speedup 1.0000x reference)
//
#include <hip/hip_runtime.h>

// BLAMem: truncated tensor-algebra (depth 4, C=8) log-signature memory.
// 5 stream-ordered dispatches (r8 structure — best measured at 126.8 us).
// Lessons: no cross-block flag sync (r6), no device-scope atomic reductions (r7),
// stride-9 padded LDS rows (r7), don't trade traffic for block count (r9/r10).
// This round: the two dominant kernels use 512-thread blocks (2 waves/SIMD) for
// latency hiding at identical traffic — r8 ran them 1 wave/SIMD, fully exposing
// ~120-cycle LDS latencies and barrier drains.

#define MEM   4680   // 8 + 64 + 512 + 4096 (unpadded global layout)
#define NG    32     // groups per batch (4 chunks each)
#define TLEN  2048
// Padded LDS signature layout: L1 [0,8), L2 [8,72), L3 rows ij*9+k at 72 (576),
// L4 rows ijk*9+l at 648 (4608). Total 5256 floats.
#define P3OFF 72
#define P4OFF 648
#define SIGSZ 5256

// padded-LDS <- unpadded-global signature row (512 threads)
__device__ __forceinline__ void load_padded512(float* dst, const float* __restrict__ src, int tid) {
    if (tid < 72) dst[tid] = src[tid];
    if (tid < 512) dst[P3OFF + (tid >> 3) * 9 + (tid & 7)] = src[72 + tid];
    for (int e = tid; e < 4096; e += 512) dst[P4OFF + (e >> 3) * 9 + (e & 7)] = src[584 + e];
}

// Load the 64 per-step increments for group (b,g) into sInc[512] (512 threads).
__device__ __forceinline__ void load_inc512(const float* __restrict__ x, int b, int g,
                                            float* sInc, int tid) {
    int s = tid >> 3, c = tid & 7;
    int t = g * 64 + s;
    float v;
    if (c < 7) {
        float cur  = x[(b * TLEN + t) * 7 + c];
        float prev = (t > 0) ? x[(b * TLEN + t - 1) * 7 + c] : 0.f;
        v = cur - prev;
    } else v = (t > 0) ? (1.f / 2047.f) : 0.f;
    sInc[tid] = v;
}

// 16-step closed-form chunk recurrence for one L4 row (i,j,k), 8 l-values.
#define CHUNK_RECUR(dch)                                                            \
    float p1 = 0.f, l2 = 0.f, l3 = 0.f;                                             \
    float S[8];                                                                     \
    _Pragma("unroll")                                                               \
    for (int l = 0; l < 8; l++) S[l] = 0.f;                                         \
    _Pragma("unroll")                                                               \
    for (int t = 0; t < 16; t++) {                                                  \
        const float* dr = (dch) + t * 8;                                            \
        float di = dr[i], dj = dr[j], dk = dr[k];                                   \
        float gg = l3 + dk * (l2 * 0.5f + dj * (p1 * (1.f/6.f) + di * (1.f/24.f))); \
        _Pragma("unroll")                                                           \
        for (int l = 0; l < 8; l++) S[l] += gg * dr[l];                             \
        l3 += dk * (l2 + dj * (p1 * 0.5f + di * (1.f/6.f)));                        \
        l2 += (p1 + di * 0.5f) * dj;                                                \
        p1 += di;                                                                   \
    }

// First chunk: write closed-form sig directly into padded sA (512 threads).
__device__ __forceinline__ void chunk_step_first(const float* dch, float* sA, int tid) {
    const int i = tid >> 6, j = (tid >> 3) & 7, k = tid & 7;
    const int row = tid >> 3, jk = tid & 63;
    CHUNK_RECUR(dch)
#pragma unroll
    for (int l = 0; l < 8; l++) sA[P4OFF + tid * 9 + l] = S[l];
    sA[P3OFF + row * 9 + k] = l3;
    if (k == 0) sA[8 + row] = l2;
    if (jk == 0) sA[i] = p1;
    __syncthreads();
    (void)j;
}

// Subsequent chunk: closed form + fold into running padded product sA (512 threads).
// U scratch: loc3 padded 576 | loc2 64 | loc1 8 = 648 floats.
__device__ __forceinline__ void chunk_step(const float* dch, float* sA, float* U, int tid) {
    float* loc3 = U;
    float* loc2 = U + 576;
    float* loc1 = U + 640;
    const int i = tid >> 6, j = (tid >> 3) & 7, k = tid & 7;
    const int row = tid >> 3, jk = tid & 63;
    CHUNK_RECUR(dch)
    loc3[row * 9 + k] = l3;
    if (k == 0) loc2[row] = l2;
    if (jk == 0) loc1[i] = p1;
    __syncthreads();
    float a1 = sA[i], a2 = sA[8 + row], a3 = sA[P3OFF + row * 9 + k];
    const float* l3p = &loc3[jk * 9];
    const float* l2p = &loc2[k * 8];
    float n4[8];
#pragma unroll
    for (int l = 0; l < 8; l++)
        n4[l] = sA[P4OFF + tid * 9 + l] + S[l] + a1 * l3p[l] + a2 * l2p[l] + a3 * loc1[l];
    float n3 = a3 + l3 + a1 * loc2[jk] + a2 * loc1[k];
    float n2v = 0.f, n1v = 0.f;
    if (tid < 64) n2v = sA[8 + tid] + loc2[tid] + sA[tid >> 3] * loc1[tid & 7];
    if (tid < 8)  n1v = sA[tid] + loc1[tid];
    __syncthreads();
#pragma unroll
    for (int l = 0; l < 8; l++) sA[P4OFF + tid * 9 + l] = n4[l];
    sA[P3OFF + row * 9 + k] = n3;
    if (tid < 64) sA[8 + tid] = n2v;
    if (tid < 8)  sA[tid] = n1v;
    __syncthreads();
    (void)j;
}

// ------------------------------------------------ kernel 1: group totals (grid 256 x 512t)
__global__ __launch_bounds__(512) void sig_totals_kernel(const float* __restrict__ x,
                                                         float* __restrict__ T) {
    int blk = blockIdx.x;
    int b = blk >> 5, g = blk & 31;
    int tid = threadIdx.x;
    __shared__ __attribute__((aligned(16))) float sInc[512];
    __shared__ __attribute__((aligned(16))) float sA[SIGSZ];
    __shared__ __attribute__((aligned(16))) float U[648];

    load_inc512(x, b, g, sInc, tid);
    __syncthreads();
    chunk_step_first(&sInc[0], sA, tid);
    chunk_step(&sInc[128], sA, U, tid);
    chunk_step(&sInc[256], sA, U, tid);
    chunk_step(&sInc[384], sA, U, tid);

    size_t base = (size_t)blk * MEM;
    for (int m = tid; m < MEM; m += 512) {
        float v;
        if (m < 72) v = sA[m];
        else if (m < 584) { int e = m - 72;  v = sA[P3OFF + (e >> 3) * 9 + (e & 7)]; }
        else              { int e = m - 584; v = sA[P4OFF + (e >> 3) * 9 + (e & 7)]; }
        T[base + m] = v;
    }
}

// ------------------------------------------------ kernel 2: cascade scan T -> P (grid 128 x 256t)
__global__ __launch_bounds__(256) void scan_fused_kernel(const float* __restrict__ T,
                                                         float* __restrict__ P) {
    int bx = blockIdx.x;
    int b = bx >> 4, s = bx & 15;
    int tid = threadIdx.x;

    __shared__ float st1[NG][8];
    __shared__ float st2[NG][64];
    __shared__ float st3[NG][32];
    __shared__ float sp1[NG][8];
    __shared__ float sp2[NG][64];
    __shared__ float sp3[NG][32];

    int bBase = b * NG;
    {
        int g = tid >> 3, i = tid & 7;
        st1[g][i] = T[(size_t)(bBase + g) * MEM + i];
    }
    for (int m = tid; m < NG * 64; m += 256) {
        int g = m >> 6, e = m & 63;
        st2[g][e] = T[(size_t)(bBase + g) * MEM + 8 + e];
    }
    for (int m = tid; m < NG * 32; m += 256) {
        int g = m >> 5, e = m & 31;
        st3[g][e] = T[(size_t)(bBase + g) * MEM + 72 + s * 32 + e];
    }
    __syncthreads();

    if (tid < 64) {
        int i = tid >> 3, k = tid & 7;
        float p1acc = 0.f, p2acc = 0.f;
        for (int g = 0; g < NG; g++) {
            sp2[g][tid] = p2acc;
            if (k == 0) sp1[g][i] = p1acc;
            if (s == 0) {
                size_t prow = (size_t)(bBase + g) * MEM;
                P[prow + 8 + tid] = p2acc;
                if (k == 0) P[prow + i] = p1acc;
            }
            p2acc += st2[g][tid] + p1acc * st1[g][k];
            p1acc += st1[g][i];
        }
    }
    __syncthreads();
    if (tid < 32) {
        int ijk = s * 32 + tid;
        int i = ijk >> 6, jk = ijk & 63, ij = ijk >> 3, k = ijk & 7;
        float acc3 = 0.f;
        for (int g = 0; g < NG; g++) {
            sp3[g][tid] = acc3;
            P[(size_t)(bBase + g) * MEM + 72 + ijk] = acc3;
            acc3 += st3[g][tid] + sp1[g][i] * st2[g][jk] + sp2[g][ij] * st1[g][k];
        }
    }
    __syncthreads();
    {
        int m = s * 256 + tid;
        int i = m >> 9, jkl = m & 511, ij = m >> 6, kl = m & 63, l = m & 7;
        int p3loc = tid >> 3;
        float acc4 = 0.f;
#pragma unroll 4
        for (int g = 0; g < NG; g++) {
            size_t row = (size_t)(bBase + g) * MEM;
            P[row + 584 + m] = acc4;
            acc4 += T[row + 584 + m]
                  + sp1[g][i] * T[row + 72 + jkl]
                  + sp2[g][ij] * st2[g][kl]
                  + sp3[g][p3loc] * st1[g][l];
        }
    }
}

// ------------------------------------------------ kernel 3: recompute chunks + apply + log
// grid 256 x 512t, block (b,g): per chunk, R = P[b,g] (x) cum; accumulate ta_log(R).
__global__ __launch_bounds__(512) void apply_log_pool_kernel(const float* __restrict__ x,
                                                             const float* __restrict__ P,
                                                             float* __restrict__ partial) {
    int blk = blockIdx.x;
    int b = blk >> 5, g = blk & 31;
    int tid = threadIdx.x;

    __shared__ __attribute__((aligned(16))) float sInc[512];
    __shared__ __attribute__((aligned(16))) float sA[SIGSZ];
    __shared__ __attribute__((aligned(16))) float sP[SIGSZ];
    __shared__ __attribute__((aligned(16))) float U[648];
    __shared__ __attribute__((aligned(16))) float sR[648];    // L1 8 | L2 64 | L3 pad 576
    __shared__ __attribute__((aligned(16))) float sQ23[576];  // padded rows of 9

    load_inc512(x, b, g, sInc, tid);
    load_padded512(sP, P + (size_t)blk * MEM, tid);
    __syncthreads();

    const int i = tid >> 6, j = (tid >> 3) & 7, k = tid & 7;
    const int row = tid >> 3, jk = tid & 63;

    float pool4[8];
#pragma unroll
    for (int l = 0; l < 8; l++) pool4[l] = 0.f;
    float pool3 = 0.f, pool2 = 0.f, pool1 = 0.f;

    for (int c = 0; c < 4; c++) {
        if (c == 0) chunk_step_first(&sInc[0], sA, tid);
        else        chunk_step(&sInc[c * 128], sA, U, tid);

        float a1 = sP[i], a2 = sP[8 + row], a3 = sP[P3OFF + row * 9 + k];
        const float* b3p = &sA[P3OFF + jk * 9];
        const float* b2p = &sA[8 + k * 8];
        float R4[8];
#pragma unroll
        for (int l = 0; l < 8; l++)
            R4[l] = sP[P4OFF + tid * 9 + l] + sA[P4OFF + tid * 9 + l]
                  + a1 * b3p[l] + a2 * b2p[l] + a3 * sA[l];
        float R3 = a3 + sA[P3OFF + row * 9 + k] + a1 * sA[8 + jk] + a2 * sA[k];
        float R2v = 0.f, R1v = 0.f;
        if (tid < 64) R2v = sP[8 + tid] + sA[8 + tid] + sP[tid >> 3] * sA[tid & 7];
        if (tid < 8)  R1v = sP[tid] + sA[tid];

        sR[P3OFF + row * 9 + k] = R3;
        if (tid < 64) sR[8 + tid] = R2v;
        if (tid < 8)  sR[tid] = R1v;
        __syncthreads();

        float q23 = sR[i] * sR[8 + jk] + sR[8 + row] * sR[k];
        sQ23[row * 9 + k] = q23;
        __syncthreads();

        {
            float s1i = sR[i], s1j = sR[j], s1k = sR[k];
            float s2ij = sR[8 + row];
            const float* r3p = &sR[P3OFF + jk * 9];
            const float* r2p = &sR[8 + k * 8];
            const float* q23p = &sQ23[jk * 9];
#pragma unroll
            for (int l = 0; l < 8; l++) {
                float s1l = sR[l];
                float p22 = s1k * s1l;
                float p24 = s1i * r3p[l] + s2ij * r2p[l] + R3 * s1l;
                float p34 = s1i * q23p[l] + s2ij * p22;
                float p44 = s1i * s1j * p22;
                pool4[l] += R4[l] - 0.5f * p24 + (1.f/3.f) * p34 - 0.25f * p44;
            }
            pool3 += R3 - 0.5f * q23 + (1.f/3.f) * s1i * s1j * s1k;
            if (tid < 64) pool2 += R2v - 0.5f * sR[tid >> 3] * sR[tid & 7];
            if (tid < 8)  pool1 += R1v;
        }
        __syncthreads();   // sR/sQ23 reads done before next iteration overwrites
    }

    {
        float* pb = partial + (size_t)blk * MEM;
        float4* d1 = (float4*)(pb + 584 + tid * 8);
        d1[0] = make_float4(pool4[0], pool4[1], pool4[2], pool4[3]);
        d1[1] = make_float4(pool4[4], pool4[5], pool4[6], pool4[7]);
        pb[72 + tid] = pool3;
        if (tid < 64) pb[8 + tid] = pool2;
        if (tid < 8)  pb[tid] = pool1;
    }
}

// ------------------------------------------------ kernel 4: reduce partials + gemv -> hpart
__global__ __launch_bounds__(256) void gemv1_kernel(const float* __restrict__ partial,
                                                    const float* __restrict__ W1,
                                                    float* __restrict__ hpart) {
    int kc = blockIdx.x;
    int tid = threadIdx.x;
    int k0 = kc * 32;
    __shared__ float sp[8][32];
    {
        int b = tid >> 5, k = tid & 31;
        float sum = 0.f;
        if (k0 + k < MEM) {
#pragma unroll 4
            for (int g = 0; g < NG; g++)
                sum += partial[(size_t)(b * NG + g) * MEM + k0 + k];
        }
        sp[b][k] = sum * (1.f / 128.f);
    }
    __syncthreads();
    float acc[8];
#pragma unroll
    for (int b = 0; b < 8; b++) acc[b] = 0.f;
    int kend = (k0 + 32 < MEM) ? 32 : (MEM - k0);
    for (int k = 0; k < kend; k++) {
        float wv = W1[(size_t)(k0 + k) * 256 + tid];
#pragma unroll
        for (int b = 0; b < 8; b++) acc[b] += sp[b][k] * wv;
    }
#pragma unroll
    for (int b = 0; b < 8; b++) hpart[(size_t)kc * 2048 + b * 256 + tid] = acc[b];
}

// ------------------------------------------------ kernel 5: reduce hpart + final MLP
__global__ __launch_bounds__(256) void final_kernel(const float* __restrict__ hpart,
                                                    const float* __restrict__ b1,
                                                    const float* __restrict__ W2,
                                                    const float* __restrict__ b2,
                                                    float* __restrict__ outp) {
    int b = blockIdx.x;
    int tid = threadIdx.x;
    float v = 0.f;
    for (int kc = 0; kc < 147; kc++) v += hpart[(size_t)kc * 2048 + b * 256 + tid];
    v += b1[tid];
    v = fmaxf(v, 0.f) * W2[tid];
    __shared__ float sRed[256];
    sRed[tid] = v;
    __syncthreads();
    for (int s = 128; s > 0; s >>= 1) {
        if (tid < s) sRed[tid] += sRed[tid + s];
        __syncthreads();
    }
    if (tid == 0) outp[b] = sRed[0] + b2[0];
}

// ------------------------------------------------ launch
extern "C" void kernel_launch(void* const* d_in, const int* in_sizes, int n_in,
                              void* d_out, int out_size, void* d_ws, size_t ws_size,
                              hipStream_t stream) {
    const float* x  = (const float*)d_in[0];
    const float* W1 = (const float*)d_in[1];
    const float* b1 = (const float*)d_in[2];
    const float* W2 = (const float*)d_in[3];
    const float* b2 = (const float*)d_in[4];
    float* out = (float*)d_out;

    float* ws = (float*)d_ws;
    float* T       = ws;                            // 256*MEM (group totals)
    float* P       = T + (size_t)256 * MEM;         // 256*MEM (exclusive prefixes)
    float* partial = P + (size_t)256 * MEM;         // 256*MEM (pooled partials)
    float* hpart   = partial + (size_t)256 * MEM;   // 147*2048

    sig_totals_kernel<<<256, 512, 0, stream>>>(x, T);
    scan_fused_kernel<<<128, 256, 0, stream>>>(T, P);
    apply_log_pool_kernel<<<256, 512, 0, stream>>>(x, P, partial);
    gemv1_kernel<<<147, 256, 0, stream>>>(partial, W1, hpart);
    final_kernel<<<8, 256, 0, stream>>>(hpart, b1, W2, b2, out);
}

// Round 12
// 159.504 us; speedup vs baseline: 1.0147x; 1.0147x over previous
//
#include <hip/hip_runtime.h>

// BLAMem: truncated tensor-algebra (depth 4, C=8) log-signature memory.
// 5 stream-ordered dispatches. Lessons: no cross-block flag sync (r6), no
// device-scope atomic reductions (r7), stride-9 padded LDS rows (r7), don't
// trade traffic for block count (r9/r10), and — r11 — __launch_bounds__(512)
// without a waves/EU hint caps VGPR at 128 and spills ~65 MB of scratch to HBM.
// This round: identical to r11 but __launch_bounds__(512, 2) on the two
// 512-thread kernels -> 256-VGPR budget, no spill, 2 waves/SIMD latency hiding.

#define MEM   4680   // 8 + 64 + 512 + 4096 (unpadded global layout)
#define NG    32     // groups per batch (4 chunks each)
#define TLEN  2048
// Padded LDS signature layout: L1 [0,8), L2 [8,72), L3 rows ij*9+k at 72 (576),
// L4 rows ijk*9+l at 648 (4608). Total 5256 floats.
#define P3OFF 72
#define P4OFF 648
#define SIGSZ 5256

// padded-LDS <- unpadded-global signature row (512 threads)
__device__ __forceinline__ void load_padded512(float* dst, const float* __restrict__ src, int tid) {
    if (tid < 72) dst[tid] = src[tid];
    if (tid < 512) dst[P3OFF + (tid >> 3) * 9 + (tid & 7)] = src[72 + tid];
    for (int e = tid; e < 4096; e += 512) dst[P4OFF + (e >> 3) * 9 + (e & 7)] = src[584 + e];
}

// Load the 64 per-step increments for group (b,g) into sInc[512] (512 threads).
__device__ __forceinline__ void load_inc512(const float* __restrict__ x, int b, int g,
                                            float* sInc, int tid) {
    int s = tid >> 3, c = tid & 7;
    int t = g * 64 + s;
    float v;
    if (c < 7) {
        float cur  = x[(b * TLEN + t) * 7 + c];
        float prev = (t > 0) ? x[(b * TLEN + t - 1) * 7 + c] : 0.f;
        v = cur - prev;
    } else v = (t > 0) ? (1.f / 2047.f) : 0.f;
    sInc[tid] = v;
}

// 16-step closed-form chunk recurrence for one L4 row (i,j,k), 8 l-values.
#define CHUNK_RECUR(dch)                                                            \
    float p1 = 0.f, l2 = 0.f, l3 = 0.f;                                             \
    float S[8];                                                                     \
    _Pragma("unroll")                                                               \
    for (int l = 0; l < 8; l++) S[l] = 0.f;                                         \
    _Pragma("unroll")                                                               \
    for (int t = 0; t < 16; t++) {                                                  \
        const float* dr = (dch) + t * 8;                                            \
        float di = dr[i], dj = dr[j], dk = dr[k];                                   \
        float gg = l3 + dk * (l2 * 0.5f + dj * (p1 * (1.f/6.f) + di * (1.f/24.f))); \
        _Pragma("unroll")                                                           \
        for (int l = 0; l < 8; l++) S[l] += gg * dr[l];                             \
        l3 += dk * (l2 + dj * (p1 * 0.5f + di * (1.f/6.f)));                        \
        l2 += (p1 + di * 0.5f) * dj;                                                \
        p1 += di;                                                                   \
    }

// First chunk: write closed-form sig directly into padded sA (512 threads).
__device__ __forceinline__ void chunk_step_first(const float* dch, float* sA, int tid) {
    const int i = tid >> 6, j = (tid >> 3) & 7, k = tid & 7;
    const int row = tid >> 3, jk = tid & 63;
    CHUNK_RECUR(dch)
#pragma unroll
    for (int l = 0; l < 8; l++) sA[P4OFF + tid * 9 + l] = S[l];
    sA[P3OFF + row * 9 + k] = l3;
    if (k == 0) sA[8 + row] = l2;
    if (jk == 0) sA[i] = p1;
    __syncthreads();
    (void)j;
}

// Subsequent chunk: closed form + fold into running padded product sA (512 threads).
// U scratch: loc3 padded 576 | loc2 64 | loc1 8 = 648 floats.
__device__ __forceinline__ void chunk_step(const float* dch, float* sA, float* U, int tid) {
    float* loc3 = U;
    float* loc2 = U + 576;
    float* loc1 = U + 640;
    const int i = tid >> 6, j = (tid >> 3) & 7, k = tid & 7;
    const int row = tid >> 3, jk = tid & 63;
    CHUNK_RECUR(dch)
    loc3[row * 9 + k] = l3;
    if (k == 0) loc2[row] = l2;
    if (jk == 0) loc1[i] = p1;
    __syncthreads();
    float a1 = sA[i], a2 = sA[8 + row], a3 = sA[P3OFF + row * 9 + k];
    const float* l3p = &loc3[jk * 9];
    const float* l2p = &loc2[k * 8];
    float n4[8];
#pragma unroll
    for (int l = 0; l < 8; l++)
        n4[l] = sA[P4OFF + tid * 9 + l] + S[l] + a1 * l3p[l] + a2 * l2p[l] + a3 * loc1[l];
    float n3 = a3 + l3 + a1 * loc2[jk] + a2 * loc1[k];
    float n2v = 0.f, n1v = 0.f;
    if (tid < 64) n2v = sA[8 + tid] + loc2[tid] + sA[tid >> 3] * loc1[tid & 7];
    if (tid < 8)  n1v = sA[tid] + loc1[tid];
    __syncthreads();
#pragma unroll
    for (int l = 0; l < 8; l++) sA[P4OFF + tid * 9 + l] = n4[l];
    sA[P3OFF + row * 9 + k] = n3;
    if (tid < 64) sA[8 + tid] = n2v;
    if (tid < 8)  sA[tid] = n1v;
    __syncthreads();
    (void)j;
}

// ------------------------------------------------ kernel 1: group totals (grid 256 x 512t)
__global__ __launch_bounds__(512, 2) void sig_totals_kernel(const float* __restrict__ x,
                                                            float* __restrict__ T) {
    int blk = blockIdx.x;
    int b = blk >> 5, g = blk & 31;
    int tid = threadIdx.x;
    __shared__ __attribute__((aligned(16))) float sInc[512];
    __shared__ __attribute__((aligned(16))) float sA[SIGSZ];
    __shared__ __attribute__((aligned(16))) float U[648];

    load_inc512(x, b, g, sInc, tid);
    __syncthreads();
    chunk_step_first(&sInc[0], sA, tid);
    chunk_step(&sInc[128], sA, U, tid);
    chunk_step(&sInc[256], sA, U, tid);
    chunk_step(&sInc[384], sA, U, tid);

    size_t base = (size_t)blk * MEM;
    for (int m = tid; m < MEM; m += 512) {
        float v;
        if (m < 72) v = sA[m];
        else if (m < 584) { int e = m - 72;  v = sA[P3OFF + (e >> 3) * 9 + (e & 7)]; }
        else              { int e = m - 584; v = sA[P4OFF + (e >> 3) * 9 + (e & 7)]; }
        T[base + m] = v;
    }
}

// ------------------------------------------------ kernel 2: cascade scan T -> P (grid 128 x 256t)
__global__ __launch_bounds__(256) void scan_fused_kernel(const float* __restrict__ T,
                                                         float* __restrict__ P) {
    int bx = blockIdx.x;
    int b = bx >> 4, s = bx & 15;
    int tid = threadIdx.x;

    __shared__ float st1[NG][8];
    __shared__ float st2[NG][64];
    __shared__ float st3[NG][32];
    __shared__ float sp1[NG][8];
    __shared__ float sp2[NG][64];
    __shared__ float sp3[NG][32];

    int bBase = b * NG;
    {
        int g = tid >> 3, i = tid & 7;
        st1[g][i] = T[(size_t)(bBase + g) * MEM + i];
    }
    for (int m = tid; m < NG * 64; m += 256) {
        int g = m >> 6, e = m & 63;
        st2[g][e] = T[(size_t)(bBase + g) * MEM + 8 + e];
    }
    for (int m = tid; m < NG * 32; m += 256) {
        int g = m >> 5, e = m & 31;
        st3[g][e] = T[(size_t)(bBase + g) * MEM + 72 + s * 32 + e];
    }
    __syncthreads();

    if (tid < 64) {
        int i = tid >> 3, k = tid & 7;
        float p1acc = 0.f, p2acc = 0.f;
        for (int g = 0; g < NG; g++) {
            sp2[g][tid] = p2acc;
            if (k == 0) sp1[g][i] = p1acc;
            if (s == 0) {
                size_t prow = (size_t)(bBase + g) * MEM;
                P[prow + 8 + tid] = p2acc;
                if (k == 0) P[prow + i] = p1acc;
            }
            p2acc += st2[g][tid] + p1acc * st1[g][k];
            p1acc += st1[g][i];
        }
    }
    __syncthreads();
    if (tid < 32) {
        int ijk = s * 32 + tid;
        int i = ijk >> 6, jk = ijk & 63, ij = ijk >> 3, k = ijk & 7;
        float acc3 = 0.f;
        for (int g = 0; g < NG; g++) {
            sp3[g][tid] = acc3;
            P[(size_t)(bBase + g) * MEM + 72 + ijk] = acc3;
            acc3 += st3[g][tid] + sp1[g][i] * st2[g][jk] + sp2[g][ij] * st1[g][k];
        }
    }
    __syncthreads();
    {
        int m = s * 256 + tid;
        int i = m >> 9, jkl = m & 511, ij = m >> 6, kl = m & 63, l = m & 7;
        int p3loc = tid >> 3;
        float acc4 = 0.f;
#pragma unroll 4
        for (int g = 0; g < NG; g++) {
            size_t row = (size_t)(bBase + g) * MEM;
            P[row + 584 + m] = acc4;
            acc4 += T[row + 584 + m]
                  + sp1[g][i] * T[row + 72 + jkl]
                  + sp2[g][ij] * st2[g][kl]
                  + sp3[g][p3loc] * st1[g][l];
        }
    }
}

// ------------------------------------------------ kernel 3: recompute chunks + apply + log
// grid 256 x 512t, block (b,g): per chunk, R = P[b,g] (x) cum; accumulate ta_log(R).
__global__ __launch_bounds__(512, 2) void apply_log_pool_kernel(const float* __restrict__ x,
                                                                const float* __restrict__ P,
                                                                float* __restrict__ partial) {
    int blk = blockIdx.x;
    int b = blk >> 5, g = blk & 31;
    int tid = threadIdx.x;

    __shared__ __attribute__((aligned(16))) float sInc[512];
    __shared__ __attribute__((aligned(16))) float sA[SIGSZ];
    __shared__ __attribute__((aligned(16))) float sP[SIGSZ];
    __shared__ __attribute__((aligned(16))) float U[648];
    __shared__ __attribute__((aligned(16))) float sR[648];    // L1 8 | L2 64 | L3 pad 576
    __shared__ __attribute__((aligned(16))) float sQ23[576];  // padded rows of 9

    load_inc512(x, b, g, sInc, tid);
    load_padded512(sP, P + (size_t)blk * MEM, tid);
    __syncthreads();

    const int i = tid >> 6, j = (tid >> 3) & 7, k = tid & 7;
    const int row = tid >> 3, jk = tid & 63;

    float pool4[8];
#pragma unroll
    for (int l = 0; l < 8; l++) pool4[l] = 0.f;
    float pool3 = 0.f, pool2 = 0.f, pool1 = 0.f;

    for (int c = 0; c < 4; c++) {
        if (c == 0) chunk_step_first(&sInc[0], sA, tid);
        else        chunk_step(&sInc[c * 128], sA, U, tid);

        float a1 = sP[i], a2 = sP[8 + row], a3 = sP[P3OFF + row * 9 + k];
        const float* b3p = &sA[P3OFF + jk * 9];
        const float* b2p = &sA[8 + k * 8];
        float R4[8];
#pragma unroll
        for (int l = 0; l < 8; l++)
            R4[l] = sP[P4OFF + tid * 9 + l] + sA[P4OFF + tid * 9 + l]
                  + a1 * b3p[l] + a2 * b2p[l] + a3 * sA[l];
        float R3 = a3 + sA[P3OFF + row * 9 + k] + a1 * sA[8 + jk] + a2 * sA[k];
        float R2v = 0.f, R1v = 0.f;
        if (tid < 64) R2v = sP[8 + tid] + sA[8 + tid] + sP[tid >> 3] * sA[tid & 7];
        if (tid < 8)  R1v = sP[tid] + sA[tid];

        sR[P3OFF + row * 9 + k] = R3;
        if (tid < 64) sR[8 + tid] = R2v;
        if (tid < 8)  sR[tid] = R1v;
        __syncthreads();

        float q23 = sR[i] * sR[8 + jk] + sR[8 + row] * sR[k];
        sQ23[row * 9 + k] = q23;
        __syncthreads();

        {
            float s1i = sR[i], s1j = sR[j], s1k = sR[k];
            float s2ij = sR[8 + row];
            const float* r3p = &sR[P3OFF + jk * 9];
            const float* r2p = &sR[8 + k * 8];
            const float* q23p = &sQ23[jk * 9];
#pragma unroll
            for (int l = 0; l < 8; l++) {
                float s1l = sR[l];
                float p22 = s1k * s1l;
                float p24 = s1i * r3p[l] + s2ij * r2p[l] + R3 * s1l;
                float p34 = s1i * q23p[l] + s2ij * p22;
                float p44 = s1i * s1j * p22;
                pool4[l] += R4[l] - 0.5f * p24 + (1.f/3.f) * p34 - 0.25f * p44;
            }
            pool3 += R3 - 0.5f * q23 + (1.f/3.f) * s1i * s1j * s1k;
            if (tid < 64) pool2 += R2v - 0.5f * sR[tid >> 3] * sR[tid & 7];
            if (tid < 8)  pool1 += R1v;
        }
        __syncthreads();   // sR/sQ23 reads done before next iteration overwrites
    }

    {
        float* pb = partial + (size_t)blk * MEM;
        float4* d1 = (float4*)(pb + 584 + tid * 8);
        d1[0] = make_float4(pool4[0], pool4[1], pool4[2], pool4[3]);
        d1[1] = make_float4(pool4[4], pool4[5], pool4[6], pool4[7]);
        pb[72 + tid] = pool3;
        if (tid < 64) pb[8 + tid] = pool2;
        if (tid < 8)  pb[tid] = pool1;
    }
}

// ------------------------------------------------ kernel 4: reduce partials + gemv -> hpart
__global__ __launch_bounds__(256) void gemv1_kernel(const float* __restrict__ partial,
                                                    const float* __restrict__ W1,
                                                    float* __restrict__ hpart) {
    int kc = blockIdx.x;
    int tid = threadIdx.x;
    int k0 = kc * 32;
    __shared__ float sp[8][32];
    {
        int b = tid >> 5, k = tid & 31;
        float sum = 0.f;
        if (k0 + k < MEM) {
#pragma unroll 4
            for (int g = 0; g < NG; g++)
                sum += partial[(size_t)(b * NG + g) * MEM + k0 + k];
        }
        sp[b][k] = sum * (1.f / 128.f);
    }
    __syncthreads();
    float acc[8];
#pragma unroll
    for (int b = 0; b < 8; b++) acc[b] = 0.f;
    int kend = (k0 + 32 < MEM) ? 32 : (MEM - k0);
    for (int k = 0; k < kend; k++) {
        float wv = W1[(size_t)(k0 + k) * 256 + tid];
#pragma unroll
        for (int b = 0; b < 8; b++) acc[b] += sp[b][k] * wv;
    }
#pragma unroll
    for (int b = 0; b < 8; b++) hpart[(size_t)kc * 2048 + b * 256 + tid] = acc[b];
}

// ------------------------------------------------ kernel 5: reduce hpart + final MLP
__global__ __launch_bounds__(256) void final_kernel(const float* __restrict__ hpart,
                                                    const float* __restrict__ b1,
                                                    const float* __restrict__ W2,
                                                    const float* __restrict__ b2,
                                                    float* __restrict__ outp) {
    int b = blockIdx.x;
    int tid = threadIdx.x;
    float v = 0.f;
    for (int kc = 0; kc < 147; kc++) v += hpart[(size_t)kc * 2048 + b * 256 + tid];
    v += b1[tid];
    v = fmaxf(v, 0.f) * W2[tid];
    __shared__ float sRed[256];
    sRed[tid] = v;
    __syncthreads();
    for (int s = 128; s > 0; s >>= 1) {
        if (tid < s) sRed[tid] += sRed[tid + s];
        __syncthreads();
    }
    if (tid == 0) outp[b] = sRed[0] + b2[0];
}

// ------------------------------------------------ launch
extern "C" void kernel_launch(void* const* d_in, const int* in_sizes, int n_in,
                              void* d_out, int out_size, void* d_ws, size_t ws_size,
                              hipStream_t stream) {
    const float* x  = (const float*)d_in[0];
    const float* W1 = (const float*)d_in[1];
    const float* b1 = (const float*)d_in[2];
    const float* W2 = (const float*)d_in[3];
    const float* b2 = (const float*)d_in[4];
    float* out = (float*)d_out;

    float* ws = (float*)d_ws;
    float* T       = ws;                            // 256*MEM (group totals)
    float* P       = T + (size_t)256 * MEM;         // 256*MEM (exclusive prefixes)
    float* partial = P + (size_t)256 * MEM;         // 256*MEM (pooled partials)
    float* hpart   = partial + (size_t)256 * MEM;   // 147*2048

    sig_totals_kernel<<<256, 512, 0, stream>>>(x, T);
    scan_fused_kernel<<<128, 256, 0, stream>>>(T, P);
    apply_log_pool_kernel<<<256, 512, 0, stream>>>(x, P, partial);
    gemv1_kernel<<<147, 256, 0, stream>>>(partial, W1, hpart);
    final_kernel<<<8, 256, 0, stream>>>(hpart, b1, W2, b2, out);
}

// Round 13
// 142.428 us; speedup vs baseline: 1.1363x; 1.1199x over previous
//
#include <hip/hip_runtime.h>

// BLAMem: truncated tensor-algebra (depth 4, C=8) log-signature memory.
// 5 stream-ordered dispatches, r8 structure (best: 126.8 us). Lessons: no
// cross-block flag sync (r6), no device-scope atomic reductions (r7), stride-9
// padded LDS rows (r7), don't change scan granularity (r10), 512-thread blocks
// spill at the 128-VGPR cap regardless of launch_bounds hints (r11/r12).
// This round: apply_log_pool split into half-groups (grid 512, 2 blocks/CU)
// with redundant fold recompute — scan/sig unchanged at group=4 granularity.

#define MEM   4680   // 8 + 64 + 512 + 4096 (unpadded global layout)
#define NG    32     // groups per batch (4 chunks each) — scan granularity
#define TLEN  2048
// Padded LDS signature layout: L1 [0,8), L2 [8,72), L3 rows ij*9+k at 72 (576),
// L4 rows ijk*9+l at 648 (4608). Total 5256 floats.
#define P3OFF 72
#define P4OFF 648
#define SIGSZ 5256

// padded-LDS <- unpadded-global signature row (256 threads)
__device__ __forceinline__ void load_padded(float* dst, const float* __restrict__ src, int tid) {
    if (tid < 72) dst[tid] = src[tid];
    for (int e = tid; e < 512; e += 256) dst[P3OFF + (e >> 3) * 9 + (e & 7)] = src[72 + e];
    for (int e = tid; e < 4096; e += 256) dst[P4OFF + (e >> 3) * 9 + (e & 7)] = src[584 + e];
}

// Load the 64 per-step increments for group (b,g) into sInc[512] (256 threads).
__device__ __forceinline__ void load_inc64(const float* __restrict__ x, int b, int g,
                                           float* sInc, int tid) {
    for (int e = tid; e < 512; e += 256) {
        int s = e >> 3, c = e & 7;
        int t = g * 64 + s;
        float v;
        if (c < 7) {
            float cur  = x[(b * TLEN + t) * 7 + c];
            float prev = (t > 0) ? x[(b * TLEN + t - 1) * 7 + c] : 0.f;
            v = cur - prev;
        } else v = (t > 0) ? (1.f / 2047.f) : 0.f;
        sInc[e] = v;
    }
}

// 16-step closed-form chunk recurrence, TWO L4 rows per thread (pos tid, tid+256).
#define CHUNK_RECUR2(dch)                                                           \
    float p1a = 0.f, l2a = 0.f, l3a = 0.f, p1b = 0.f, l2b = 0.f, l3b = 0.f;         \
    float Sa[8], Sb[8];                                                             \
    _Pragma("unroll")                                                               \
    for (int l = 0; l < 8; l++) { Sa[l] = 0.f; Sb[l] = 0.f; }                       \
    _Pragma("unroll")                                                               \
    for (int t = 0; t < 16; t++) {                                                  \
        const float* dr = (dch) + t * 8;                                            \
        float di1 = dr[i1], di2 = dr[i2], dj = dr[j1], dk = dr[k1];                 \
        float ga = l3a + dk * (l2a * 0.5f + dj * (p1a * (1.f/6.f) + di1 * (1.f/24.f))); \
        float gb = l3b + dk * (l2b * 0.5f + dj * (p1b * (1.f/6.f) + di2 * (1.f/24.f))); \
        _Pragma("unroll")                                                           \
        for (int l = 0; l < 8; l++) { float dv = dr[l]; Sa[l] += ga * dv; Sb[l] += gb * dv; } \
        l3a += dk * (l2a + dj * (p1a * 0.5f + di1 * (1.f/6.f)));                    \
        l3b += dk * (l2b + dj * (p1b * 0.5f + di2 * (1.f/6.f)));                    \
        l2a += (p1a + di1 * 0.5f) * dj;                                             \
        l2b += (p1b + di2 * 0.5f) * dj;                                             \
        p1a += di1; p1b += di2;                                                     \
    }

// First chunk: write closed-form sig directly into padded sA (verified r10).
__device__ __forceinline__ void chunk_step_first(const float* dch, float* sA, int tid) {
    const int i1 = tid >> 6, j1 = (tid >> 3) & 7, k1 = tid & 7;
    const int row1 = tid >> 3, row2 = row1 + 32;
    const int pos2 = tid + 256, i2 = pos2 >> 6;
    CHUNK_RECUR2(dch)
#pragma unroll
    for (int l = 0; l < 8; l++) { sA[P4OFF + tid * 9 + l] = Sa[l]; sA[P4OFF + pos2 * 9 + l] = Sb[l]; }
    sA[P3OFF + row1 * 9 + k1] = l3a;
    sA[P3OFF + row2 * 9 + k1] = l3b;
    if (k1 == 0) { sA[8 + row1] = l2a; sA[8 + row2] = l2b; }
    if ((tid & 63) == 0) { sA[i1] = p1a; sA[i2] = p1b; }
    __syncthreads();
    (void)j1;
}

// Subsequent chunk: closed form + fold into running padded product sA (verified r8/r10).
// U scratch: loc3 padded 576 | loc2 64 | loc1 8 = 648 floats.
__device__ __forceinline__ void chunk_step(const float* dch, float* sA, float* U, int tid) {
    float* loc3 = U;
    float* loc2 = U + 576;
    float* loc1 = U + 640;
    const int i1 = tid >> 6, j1 = (tid >> 3) & 7, k1 = tid & 7;
    const int row1 = tid >> 3, row2 = row1 + 32;
    const int jk = tid & 63;
    const int pos2 = tid + 256, i2 = pos2 >> 6;
    CHUNK_RECUR2(dch)
    loc3[row1 * 9 + k1] = l3a;
    loc3[row2 * 9 + k1] = l3b;
    if (k1 == 0) { loc2[row1] = l2a; loc2[row2] = l2b; }
    if (jk == 0) { loc1[i1] = p1a; loc1[i2] = p1b; }
    __syncthreads();
    float a1 = sA[i1], a2 = sA[8 + row1], a3 = sA[P3OFF + row1 * 9 + k1];
    float c1_ = sA[i2], c2_ = sA[8 + row2], c3_ = sA[P3OFF + row2 * 9 + k1];
    const float* l3p = &loc3[jk * 9];
    const float* l2p = &loc2[k1 * 8];
    float n4a[8], n4b[8];
#pragma unroll
    for (int l = 0; l < 8; l++) {
        float v3 = l3p[l], v2 = l2p[l], v1 = loc1[l];
        n4a[l] = sA[P4OFF + tid * 9 + l]  + Sa[l] + a1 * v3 + a2 * v2 + a3 * v1;
        n4b[l] = sA[P4OFF + pos2 * 9 + l] + Sb[l] + c1_ * v3 + c2_ * v2 + c3_ * v1;
    }
    float n3a = a3 + l3a + a1 * loc2[jk] + a2 * loc1[k1];
    float n3b = c3_ + l3b + c1_ * loc2[jk] + c2_ * loc1[k1];
    float n2v = 0.f, n1v = 0.f;
    if (tid < 64) n2v = sA[8 + tid] + loc2[tid] + sA[tid >> 3] * loc1[tid & 7];
    if (tid < 8)  n1v = sA[tid] + loc1[tid];
    __syncthreads();
#pragma unroll
    for (int l = 0; l < 8; l++) { sA[P4OFF + tid * 9 + l] = n4a[l]; sA[P4OFF + pos2 * 9 + l] = n4b[l]; }
    sA[P3OFF + row1 * 9 + k1] = n3a;
    sA[P3OFF + row2 * 9 + k1] = n3b;
    if (tid < 64) sA[8 + tid] = n2v;
    if (tid < 8)  sA[tid] = n1v;
    __syncthreads();
    (void)j1;
}

// ------------------------------------------------ kernel 1: group totals (grid 256 x 256t)
__global__ __launch_bounds__(256) void sig_totals_kernel(const float* __restrict__ x,
                                                         float* __restrict__ T) {
    int blk = blockIdx.x;
    int b = blk >> 5, g = blk & 31;
    int tid = threadIdx.x;
    __shared__ __attribute__((aligned(16))) float sInc[512];
    __shared__ __attribute__((aligned(16))) float sA[SIGSZ];
    __shared__ __attribute__((aligned(16))) float U[648];

    load_inc64(x, b, g, sInc, tid);
    __syncthreads();
    chunk_step_first(&sInc[0], sA, tid);
    chunk_step(&sInc[128], sA, U, tid);
    chunk_step(&sInc[256], sA, U, tid);
    chunk_step(&sInc[384], sA, U, tid);

    size_t base = (size_t)blk * MEM;
    for (int m = tid; m < MEM; m += 256) {
        float v;
        if (m < 72) v = sA[m];
        else if (m < 584) { int e = m - 72;  v = sA[P3OFF + (e >> 3) * 9 + (e & 7)]; }
        else              { int e = m - 584; v = sA[P4OFF + (e >> 3) * 9 + (e & 7)]; }
        T[base + m] = v;
    }
}

// ------------------------------------------------ kernel 2: cascade scan T -> P (grid 128 x 256t)
__global__ __launch_bounds__(256) void scan_fused_kernel(const float* __restrict__ T,
                                                         float* __restrict__ P) {
    int bx = blockIdx.x;
    int b = bx >> 4, s = bx & 15;
    int tid = threadIdx.x;

    __shared__ float st1[NG][8];
    __shared__ float st2[NG][64];
    __shared__ float st3[NG][32];
    __shared__ float sp1[NG][8];
    __shared__ float sp2[NG][64];
    __shared__ float sp3[NG][32];

    int bBase = b * NG;
    {
        int g = tid >> 3, i = tid & 7;
        st1[g][i] = T[(size_t)(bBase + g) * MEM + i];
    }
    for (int m = tid; m < NG * 64; m += 256) {
        int g = m >> 6, e = m & 63;
        st2[g][e] = T[(size_t)(bBase + g) * MEM + 8 + e];
    }
    for (int m = tid; m < NG * 32; m += 256) {
        int g = m >> 5, e = m & 31;
        st3[g][e] = T[(size_t)(bBase + g) * MEM + 72 + s * 32 + e];
    }
    __syncthreads();

    if (tid < 64) {
        int i = tid >> 3, k = tid & 7;
        float p1acc = 0.f, p2acc = 0.f;
        for (int g = 0; g < NG; g++) {
            sp2[g][tid] = p2acc;
            if (k == 0) sp1[g][i] = p1acc;
            if (s == 0) {
                size_t prow = (size_t)(bBase + g) * MEM;
                P[prow + 8 + tid] = p2acc;
                if (k == 0) P[prow + i] = p1acc;
            }
            p2acc += st2[g][tid] + p1acc * st1[g][k];
            p1acc += st1[g][i];
        }
    }
    __syncthreads();
    if (tid < 32) {
        int ijk = s * 32 + tid;
        int i = ijk >> 6, jk = ijk & 63, ij = ijk >> 3, k = ijk & 7;
        float acc3 = 0.f;
        for (int g = 0; g < NG; g++) {
            sp3[g][tid] = acc3;
            P[(size_t)(bBase + g) * MEM + 72 + ijk] = acc3;
            acc3 += st3[g][tid] + sp1[g][i] * st2[g][jk] + sp2[g][ij] * st1[g][k];
        }
    }
    __syncthreads();
    {
        int m = s * 256 + tid;
        int i = m >> 9, jkl = m & 511, ij = m >> 6, kl = m & 63, l = m & 7;
        int p3loc = tid >> 3;
        float acc4 = 0.f;
#pragma unroll 4
        for (int g = 0; g < NG; g++) {
            size_t row = (size_t)(bBase + g) * MEM;
            P[row + 584 + m] = acc4;
            acc4 += T[row + 584 + m]
                  + sp1[g][i] * T[row + 72 + jkl]
                  + sp2[g][ij] * st2[g][kl]
                  + sp3[g][p3loc] * st1[g][l];
        }
    }
}

// ------------------------------------------------ kernel 3: apply + log, half-groups
// grid 512 x 256t, block (b,g,h): recompute folds through its half, apply+log its
// 2 chunks, write partial row blk. h=1 redundantly folds chunks 0-1 (cheap; the
// two half-blocks of a group co-schedule at 2 blocks/CU).
__global__ __launch_bounds__(256) void apply_log_pool_kernel(const float* __restrict__ x,
                                                             const float* __restrict__ P,
                                                             float* __restrict__ partial) {
    int blk = blockIdx.x;
    int b = blk >> 6, rest = blk & 63, g = rest >> 1, h = rest & 1;
    int tid = threadIdx.x;

    __shared__ __attribute__((aligned(16))) float sInc[512];
    __shared__ __attribute__((aligned(16))) float sA[SIGSZ];
    __shared__ __attribute__((aligned(16))) float sP[SIGSZ];
    __shared__ __attribute__((aligned(16))) float U[648];
    __shared__ __attribute__((aligned(16))) float sR[648];    // L1 8 | L2 64 | L3 pad 576
    __shared__ __attribute__((aligned(16))) float sQ23[576];  // padded rows of 9

    load_inc64(x, b, g, sInc, tid);
    load_padded(sP, P + (size_t)(b * NG + g) * MEM, tid);
    __syncthreads();

    const int i1 = tid >> 6, j1 = (tid >> 3) & 7, k1 = tid & 7;
    const int row1 = tid >> 3, row2 = row1 + 32;
    const int jk = tid & 63;
    const int pos2 = tid + 256, i2 = pos2 >> 6;

    float pool4a[8], pool4b[8];
#pragma unroll
    for (int l = 0; l < 8; l++) { pool4a[l] = 0.f; pool4b[l] = 0.f; }
    float pool3a = 0.f, pool3b = 0.f, pool2 = 0.f, pool1 = 0.f;

    // build cumulative up to the start of this half
    chunk_step_first(&sInc[0], sA, tid);
    if (h == 1) {
        chunk_step(&sInc[128], sA, U, tid);
        chunk_step(&sInc[256], sA, U, tid);
    }

    for (int cc = 0; cc < 2; cc++) {
        if (!(h == 0 && cc == 0)) {
            if (cc == 1) chunk_step(&sInc[(h * 2 + 1) * 128], sA, U, tid);
        }
        // (h==0,cc==0): sA already holds chunk 0 sig from chunk_step_first
        // (h==1,cc==0): sA holds cumulative through chunk 2 from the prologue
        if (h == 1 && cc == 1) { /* fold already applied above when cc==1 */ }

        float a1 = sP[i1], a2 = sP[8 + row1], a3 = sP[P3OFF + row1 * 9 + k1];
        float c1_ = sP[i2], c2_ = sP[8 + row2], c3_ = sP[P3OFF + row2 * 9 + k1];
        const float* b3p = &sA[P3OFF + jk * 9];
        const float* b2p = &sA[8 + k1 * 8];
        float R4a[8], R4b[8];
#pragma unroll
        for (int l = 0; l < 8; l++) {
            float v3 = b3p[l], v2 = b2p[l], v1 = sA[l];
            R4a[l] = sP[P4OFF + tid * 9 + l]  + sA[P4OFF + tid * 9 + l]  + a1 * v3 + a2 * v2 + a3 * v1;
            R4b[l] = sP[P4OFF + pos2 * 9 + l] + sA[P4OFF + pos2 * 9 + l] + c1_ * v3 + c2_ * v2 + c3_ * v1;
        }
        float R3a = a3 + sA[P3OFF + row1 * 9 + k1] + a1 * sA[8 + jk] + a2 * sA[k1];
        float R3b = c3_ + sA[P3OFF + row2 * 9 + k1] + c1_ * sA[8 + jk] + c2_ * sA[k1];
        float R2v = 0.f, R1v = 0.f;
        if (tid < 64) R2v = sP[8 + tid] + sA[8 + tid] + sP[tid >> 3] * sA[tid & 7];
        if (tid < 8)  R1v = sP[tid] + sA[tid];

        sR[P3OFF + row1 * 9 + k1] = R3a;
        sR[P3OFF + row2 * 9 + k1] = R3b;
        if (tid < 64) sR[8 + tid] = R2v;
        if (tid < 8)  sR[tid] = R1v;
        __syncthreads();

        float q23a = sR[i1] * sR[8 + jk] + sR[8 + row1] * sR[k1];
        float q23b = sR[i2] * sR[8 + jk] + sR[8 + row2] * sR[k1];
        sQ23[row1 * 9 + k1] = q23a;
        sQ23[row2 * 9 + k1] = q23b;
        __syncthreads();

        {
            float s1ia = sR[i1], s1ib = sR[i2], s1j = sR[j1], s1k = sR[k1];
            float s2ija = sR[8 + row1], s2ijb = sR[8 + row2];
            const float* r3p = &sR[P3OFF + jk * 9];
            const float* r2p = &sR[8 + k1 * 8];
            const float* q23p = &sQ23[jk * 9];
#pragma unroll
            for (int l = 0; l < 8; l++) {
                float s1l = sR[l];
                float p22 = s1k * s1l;
                float p24a = s1ia * r3p[l] + s2ija * r2p[l] + R3a * s1l;
                float p24b = s1ib * r3p[l] + s2ijb * r2p[l] + R3b * s1l;
                float p34a = s1ia * q23p[l] + s2ija * p22;
                float p34b = s1ib * q23p[l] + s2ijb * p22;
                float p44a = s1ia * s1j * p22;
                float p44b = s1ib * s1j * p22;
                pool4a[l] += R4a[l] - 0.5f * p24a + (1.f/3.f) * p34a - 0.25f * p44a;
                pool4b[l] += R4b[l] - 0.5f * p24b + (1.f/3.f) * p34b - 0.25f * p44b;
            }
            pool3a += R3a - 0.5f * q23a + (1.f/3.f) * s1ia * s1j * s1k;
            pool3b += R3b - 0.5f * q23b + (1.f/3.f) * s1ib * s1j * s1k;
            if (tid < 64) pool2 += R2v - 0.5f * sR[tid >> 3] * sR[tid & 7];
            if (tid < 8)  pool1 += R1v;
        }
        __syncthreads();   // sR/sQ23 reads done before next iteration overwrites
    }

    {
        float* pb = partial + (size_t)blk * MEM;
        float4* d1 = (float4*)(pb + 584 + tid * 8);
        d1[0] = make_float4(pool4a[0], pool4a[1], pool4a[2], pool4a[3]);
        d1[1] = make_float4(pool4a[4], pool4a[5], pool4a[6], pool4a[7]);
        float4* d2 = (float4*)(pb + 584 + pos2 * 8);
        d2[0] = make_float4(pool4b[0], pool4b[1], pool4b[2], pool4b[3]);
        d2[1] = make_float4(pool4b[4], pool4b[5], pool4b[6], pool4b[7]);
        pb[72 + tid] = pool3a;
        pb[72 + pos2] = pool3b;
        if (tid < 64) pb[8 + tid] = pool2;
        if (tid < 8)  pb[tid] = pool1;
    }
}

// ------------------------------------------------ kernel 4: reduce 64 partial rows + gemv
__global__ __launch_bounds__(256) void gemv1_kernel(const float* __restrict__ partial,
                                                    const float* __restrict__ W1,
                                                    float* __restrict__ hpart) {
    int kc = blockIdx.x;
    int tid = threadIdx.x;
    int k0 = kc * 32;
    __shared__ float sp[8][32];
    {
        int b = tid >> 5, k = tid & 31;
        float sum = 0.f;
        if (k0 + k < MEM) {
#pragma unroll 4
            for (int r = 0; r < 64; r++)
                sum += partial[(size_t)(b * 64 + r) * MEM + k0 + k];
        }
        sp[b][k] = sum * (1.f / 128.f);
    }
    __syncthreads();
    float acc[8];
#pragma unroll
    for (int b = 0; b < 8; b++) acc[b] = 0.f;
    int kend = (k0 + 32 < MEM) ? 32 : (MEM - k0);
    for (int k = 0; k < kend; k++) {
        float wv = W1[(size_t)(k0 + k) * 256 + tid];
#pragma unroll
        for (int b = 0; b < 8; b++) acc[b] += sp[b][k] * wv;
    }
#pragma unroll
    for (int b = 0; b < 8; b++) hpart[(size_t)kc * 2048 + b * 256 + tid] = acc[b];
}

// ------------------------------------------------ kernel 5: reduce hpart + final MLP
__global__ __launch_bounds__(256) void final_kernel(const float* __restrict__ hpart,
                                                    const float* __restrict__ b1,
                                                    const float* __restrict__ W2,
                                                    const float* __restrict__ b2,
                                                    float* __restrict__ outp) {
    int b = blockIdx.x;
    int tid = threadIdx.x;
    float v = 0.f;
    for (int kc = 0; kc < 147; kc++) v += hpart[(size_t)kc * 2048 + b * 256 + tid];
    v += b1[tid];
    v = fmaxf(v, 0.f) * W2[tid];
    __shared__ float sRed[256];
    sRed[tid] = v;
    __syncthreads();
    for (int s = 128; s > 0; s >>= 1) {
        if (tid < s) sRed[tid] += sRed[tid + s];
        __syncthreads();
    }
    if (tid == 0) outp[b] = sRed[0] + b2[0];
}

// ------------------------------------------------ launch
extern "C" void kernel_launch(void* const* d_in, const int* in_sizes, int n_in,
                              void* d_out, int out_size, void* d_ws, size_t ws_size,
                              hipStream_t stream) {
    const float* x  = (const float*)d_in[0];
    const float* W1 = (const float*)d_in[1];
    const float* b1 = (const float*)d_in[2];
    const float* W2 = (const float*)d_in[3];
    const float* b2 = (const float*)d_in[4];
    float* out = (float*)d_out;

    float* ws = (float*)d_ws;
    float* T       = ws;                            // 256*MEM (group totals)
    float* P       = T + (size_t)256 * MEM;         // 256*MEM (exclusive prefixes)
    float* partial = P + (size_t)256 * MEM;         // 512*MEM (half-group pooled partials)
    float* hpart   = partial + (size_t)512 * MEM;   // 147*2048

    sig_totals_kernel<<<256, 256, 0, stream>>>(x, T);
    scan_fused_kernel<<<128, 256, 0, stream>>>(T, P);
    apply_log_pool_kernel<<<512, 256, 0, stream>>>(x, P, partial);
    gemv1_kernel<<<147, 256, 0, stream>>>(partial, W1, hpart);
    final_kernel<<<8, 256, 0, stream>>>(hpart, b1, W2, b2, out);
}